// Round 2
// baseline (536.148 us; speedup 1.0000x reference)
//
#include <hip/hip_runtime.h>
#include <hip/hip_bf16.h>
#include <stdint.h>

// BidirectionalAttention2: two flash-attention passes over sim = v1 @ v2^T.
//  dir A: out1[l] = softmax_m(v2_mask ? -1e-7 : sim[l,m]) @ v2, rows zeroed by v1_mask
//  dir B: out2[m] = softmax_l(v1_mask ? -1e-7 : sim[l,m]) @ v1, rows zeroed by v2_mask
// Swapped-QK^T (S^T = mfma(K,Q)) + in-register online softmax, hi/lo bf16 split
// for the sim GEMM (3 mfma passes), query compaction (masked rows pre-zeroed).
// R2 fixes: (1) kmask batch offset (was using batch 0's mask for all batches);
// (2) mask dtype normalized at runtime (detector distinguishes int32 0/1 from
// packed 1-byte bool; converter writes canonical int32 masks into d_ws).

#define MASK_FILL -1e-07f

typedef unsigned short u16;
typedef __attribute__((ext_vector_type(8))) short short8;
typedef __attribute__((ext_vector_type(4))) float f32x4;
typedef __attribute__((ext_vector_type(4))) int int4v;
typedef __attribute__((ext_vector_type(4))) u16 u16x4;

#define NB 64
#define LL 1024
#define DD 256
#define BQ 64
#define BK 32
#define NKT (LL / BK)

__device__ __forceinline__ unsigned bf16_rne(float f) {
    unsigned u = __float_as_uint(f);
    return (u + 0x7fffu + ((u >> 16) & 1u)) >> 16;
}

// ---- mask dtype detection + normalization ----------------------------------
// int32 0/1 masks: every 32-bit word is 0 or 1. Packed 1-byte bools: words are
// byte-packed (e.g. 0x00010100) -> bits above bit0 set with overwhelming
// probability over 16K random words. Scan only 64KB (in-bounds under BOTH
// interpretations).
__global__ __launch_bounds__(256) void mask_detect(
    const unsigned* __restrict__ m1, const unsigned* __restrict__ m2,
    int* __restrict__ flag)
{
    unsigned acc = 0;
    for (int i = threadIdx.x; i < 16384; i += 256)
        acc |= (m1[i] | m2[i]) & ~1u;
    __shared__ unsigned red[256];
    red[threadIdx.x] = acc;
    __syncthreads();
    for (int o = 128; o; o >>= 1) {
        if (threadIdx.x < o) red[threadIdx.x] |= red[threadIdx.x + o];
        __syncthreads();
    }
    if (threadIdx.x == 0) *flag = red[0] ? 1 : 0;
}

__global__ __launch_bounds__(256) void mask_convert(
    const void* __restrict__ m, const int* __restrict__ flag,
    int* __restrict__ outm)
{
    int i = blockIdx.x * 256 + threadIdx.x;
    int v;
    if (*flag) v = ((const unsigned char*)m)[i];   // 1-byte bool path
    else       v = ((const int*)m)[i];             // int32 path
    outm[i] = v ? 1 : 0;
}

// ---- pre-pass: fp32 -> (hi, lo) bf16 split + bf16 transpose tile ------------
// grid: NB*16*4 blocks (b, ltile(16), dtile(4)), 256 threads.
__global__ __launch_bounds__(256) void prep_kernel(
    const float* __restrict__ x, u16* __restrict__ h, u16* __restrict__ lo,
    u16* __restrict__ xt)
{
    __shared__ u16 t[64][65];
    int blk = blockIdx.x;
    int b = blk >> 6, lt = (blk >> 2) & 15, dt = blk & 3;
    int l0 = lt * 64, d0 = dt * 64;
    int tid = threadIdx.x;
    int sub = tid >> 4;        // 0..15
    int c16 = tid & 15;        // 0..15 (float4 column)
#pragma unroll
    for (int p = 0; p < 4; ++p) {
        int row = p * 16 + sub;
        size_t gi = ((size_t)b * LL + l0 + row) * DD + d0 + c16 * 4;
        f32x4 v = *(const f32x4*)(x + gi);
        u16x4 hv, lv;
#pragma unroll
        for (int e = 0; e < 4; ++e) {
            unsigned hb = bf16_rne(v[e]);
            float hf = __uint_as_float(hb << 16);
            unsigned lb = bf16_rne(v[e] - hf);
            hv[e] = (u16)hb;
            lv[e] = (u16)lb;
            t[c16 * 4 + e][row] = (u16)hb;
        }
        *(u16x4*)(h + gi) = hv;
        *(u16x4*)(lo + gi) = lv;
    }
    __syncthreads();
#pragma unroll
    for (int p = 0; p < 4; ++p) {
        int d = p * 16 + sub;
        u16x4 ov;
#pragma unroll
        for (int e = 0; e < 4; ++e) ov[e] = t[d][c16 * 4 + e];
        *(u16x4*)(xt + ((size_t)b * DD + d0 + d) * LL + l0 + c16 * 4) = ov;
    }
}

// ---- pre-pass: per-batch compaction of unmasked rows ------------------------
__global__ __launch_bounds__(256) void build_qidx(
    const int* __restrict__ mask, int* __restrict__ qidx, int* __restrict__ qcnt)
{
    int b = blockIdx.x, tid = threadIdx.x;
    __shared__ int ps[256];
    const int* mb = mask + b * LL;
    int f[4], s = 0;
#pragma unroll
    for (int j = 0; j < 4; ++j) { f[j] = (mb[tid * 4 + j] == 0) ? 1 : 0; s += f[j]; }
    ps[tid] = s;
    __syncthreads();
    for (int off = 1; off < 256; off <<= 1) {
        int v = (tid >= off) ? ps[tid - off] : 0;
        __syncthreads();
        ps[tid] += v;
        __syncthreads();
    }
    int pos = (tid > 0) ? ps[tid - 1] : 0;
#pragma unroll
    for (int j = 0; j < 4; ++j)
        if (f[j]) qidx[b * LL + (pos++)] = tid * 4 + j;
    if (tid == 255) qcnt[b] = ps[255];
}

// ---- flash attention, swapped-operand layout --------------------------------
// block: 256 thr = 4 waves; wave w owns 16 compacted q rows. BK=32 keys/iter.
// S^T frag: lane holds S[q=lane&15][key = k0+rt*16+4*(lane>>4)+i].
__global__ __launch_bounds__(256, 2) void flash_kernel(
    const u16* __restrict__ qh_g, const u16* __restrict__ ql_g,
    const u16* __restrict__ kh_g, const u16* __restrict__ kl_g,
    const u16* __restrict__ vt_g, const int* __restrict__ kmask,
    const int* __restrict__ qidx, const int* __restrict__ qcnt,
    float* __restrict__ out)
{
    int b = blockIdx.x >> 4;
    int qt = blockIdx.x & 15;
    int cnt = qcnt[b];
    if (qt * BQ >= cnt) return;

    int tid = threadIdx.x;
    int w = tid >> 6, lane = tid & 63;
    int lq = lane & 15, g = lane >> 4;

    __shared__ __align__(16) u16 khi_s[BK * DD];  // [key][d], 16B chunks ^ (key&7)
    __shared__ __align__(16) u16 klo_s[BK * DD];
    __shared__ __align__(16) u16 vt_s[DD * BK];   // [d][key], chunk ^ (d&3)^((d>>2)&3)

    int qslot = qt * BQ + w * 16 + lq;
    bool qvalid = qslot < cnt;
    int qrow = qvalid ? qidx[b * LL + qslot] : 0;

    // Q fragments (B-operand): lane holds Q[q=lq][d = ks*32 + g*8 + j]
    const u16* qbh = qh_g + ((size_t)b * LL + qrow) * DD + g * 8;
    const u16* qbl = ql_g + ((size_t)b * LL + qrow) * DD + g * 8;
    short8 qhf[8], qlf[8];
#pragma unroll
    for (int ks = 0; ks < 8; ++ks) {
        qhf[ks] = *(const short8*)(qbh + ks * 32);
        qlf[ks] = *(const short8*)(qbl + ks * 32);
    }

    float m = MASK_FILL, z = 0.f;
    f32x4 o[16];
#pragma unroll
    for (int i = 0; i < 16; ++i) o[i] = (f32x4){0.f, 0.f, 0.f, 0.f};

    const size_t kv_base = (size_t)b * LL * DD;
    const size_t vt_base = (size_t)b * DD * LL;
    const int*  kmask_b = kmask + b * LL;                    // R2 FIX: batch offset
    const int pvcc = (g ^ (lq & 3) ^ ((lq >> 2) & 3)) * 8;   // VT chunk (hoisted)

    for (int kt = 0; kt < NKT; ++kt) {
        int k0 = kt * BK;
        __syncthreads();
        // stage K hi/lo + V^T via global_load_lds (linear LDS dest, pre-swizzled src)
#pragma unroll
        for (int j = 0; j < 4; ++j) {
            int n = w * 4 + j;
            unsigned phys = (unsigned)n * 1024u + (unsigned)lane * 16u;
            unsigned key = phys >> 9;
            unsigned cl = ((phys >> 4) & 31u) ^ (key & 7u);
            size_t koff = kv_base + (size_t)(k0 + (int)key) * DD + cl * 8;
            __builtin_amdgcn_global_load_lds(
                (const __attribute__((address_space(1))) void*)(kh_g + koff),
                (__attribute__((address_space(3))) void*)(&khi_s[n * 512]), 16, 0, 0);
            __builtin_amdgcn_global_load_lds(
                (const __attribute__((address_space(1))) void*)(kl_g + koff),
                (__attribute__((address_space(3))) void*)(&klo_s[n * 512]), 16, 0, 0);
            unsigned dv = (unsigned)n * 16u + ((unsigned)lane >> 2);
            unsigned cv = ((unsigned)lane & 3u) ^ (dv & 3u) ^ ((dv >> 2) & 3u);
            size_t voff = vt_base + (size_t)dv * LL + (unsigned)k0 + cv * 8;
            __builtin_amdgcn_global_load_lds(
                (const __attribute__((address_space(1))) void*)(vt_g + voff),
                (__attribute__((address_space(3))) void*)(&vt_s[n * 512]), 16, 0, 0);
        }
        __syncthreads();

        // S^T = K @ Q^T, hi/lo split (3 passes), two 16-key row tiles
        f32x4 sa0 = (f32x4){0.f, 0.f, 0.f, 0.f};
        f32x4 sa1 = (f32x4){0.f, 0.f, 0.f, 0.f};
#pragma unroll
        for (int ks = 0; ks < 8; ++ks) {
            int cidx = ((ks * 4 + g) ^ (lq & 7)) * 8;
            short8 kh0 = *(const short8*)&khi_s[lq * 256 + cidx];
            short8 kl0 = *(const short8*)&klo_s[lq * 256 + cidx];
            short8 kh1 = *(const short8*)&khi_s[(16 + lq) * 256 + cidx];
            short8 kl1 = *(const short8*)&klo_s[(16 + lq) * 256 + cidx];
            sa0 = __builtin_amdgcn_mfma_f32_16x16x32_bf16(kh0, qhf[ks], sa0, 0, 0, 0);
            sa0 = __builtin_amdgcn_mfma_f32_16x16x32_bf16(kh0, qlf[ks], sa0, 0, 0, 0);
            sa0 = __builtin_amdgcn_mfma_f32_16x16x32_bf16(kl0, qhf[ks], sa0, 0, 0, 0);
            sa1 = __builtin_amdgcn_mfma_f32_16x16x32_bf16(kh1, qhf[ks], sa1, 0, 0, 0);
            sa1 = __builtin_amdgcn_mfma_f32_16x16x32_bf16(kh1, qlf[ks], sa1, 0, 0, 0);
            sa1 = __builtin_amdgcn_mfma_f32_16x16x32_bf16(kl1, qhf[ks], sa1, 0, 0, 0);
        }

        // mask + online softmax (per-lane column q)
        int4v mk0 = *(const int4v*)&kmask_b[k0 + 4 * g];
        int4v mk1 = *(const int4v*)&kmask_b[k0 + 16 + 4 * g];
        float s[8];
#pragma unroll
        for (int i = 0; i < 4; ++i) {
            s[i]     = mk0[i] ? MASK_FILL : sa0[i];
            s[4 + i] = mk1[i] ? MASK_FILL : sa1[i];
        }
        float pmax = s[0];
#pragma unroll
        for (int i = 1; i < 8; ++i) pmax = fmaxf(pmax, s[i]);
        pmax = fmaxf(pmax, __shfl_xor(pmax, 16));
        pmax = fmaxf(pmax, __shfl_xor(pmax, 32));
        if (__any(pmax > m)) {          // exact deferred rescale
            float mnew = fmaxf(m, pmax);
            float alpha = __expf(m - mnew);
            z *= alpha;
#pragma unroll
            for (int i = 0; i < 16; ++i) o[i] *= alpha;
            m = mnew;
        }
        float p[8], ps = 0.f;
#pragma unroll
        for (int i = 0; i < 8; ++i) { p[i] = __expf(s[i] - m); ps += p[i]; }
        ps += __shfl_xor(ps, 16);
        ps += __shfl_xor(ps, 32);
        z += ps;

        // P -> PV B-fragment (keys 8g..8g+7 at q=lq), in-register exchange
        unsigned pk00 = bf16_rne(p[0]) | (bf16_rne(p[1]) << 16);
        unsigned pk01 = bf16_rne(p[2]) | (bf16_rne(p[3]) << 16);
        unsigned pk10 = bf16_rne(p[4]) | (bf16_rne(p[5]) << 16);
        unsigned pk11 = bf16_rne(p[6]) | (bf16_rne(p[7]) << 16);
        int srcA = ((lane & 16) << 1) | lq;   // group 2*(g&1), same q
        int srcB = srcA + 16;
        unsigned a00 = (unsigned)__shfl((int)pk00, srcA);
        unsigned a01 = (unsigned)__shfl((int)pk01, srcA);
        unsigned a10 = (unsigned)__shfl((int)pk10, srcA);
        unsigned a11 = (unsigned)__shfl((int)pk11, srcA);
        unsigned b00 = (unsigned)__shfl((int)pk00, srcB);
        unsigned b01 = (unsigned)__shfl((int)pk01, srcB);
        unsigned b10 = (unsigned)__shfl((int)pk10, srcB);
        unsigned b11 = (unsigned)__shfl((int)pk11, srcB);
        bool sel = (g >> 1) != 0;             // upper 16 keys use rt=1 packs
        union { unsigned u[4]; short8 v; } pf;
        pf.u[0] = sel ? a10 : a00;
        pf.u[1] = sel ? a11 : a01;
        pf.u[2] = sel ? b10 : b00;
        pf.u[3] = sel ? b11 : b01;

        // O^T += V^T @ P^T  (A = V^T rows d, B = P^T)
#pragma unroll
        for (int dt = 0; dt < 16; ++dt) {
            int d = dt * 16 + lq;
            short8 vf = *(const short8*)&vt_s[d * 32 + pvcc];
            o[dt] = __builtin_amdgcn_mfma_f32_16x16x32_bf16(vf, pf.v, o[dt], 0, 0, 0);
        }
    }

    if (qvalid) {
        float zinv = 1.0f / z;
        float* orow = out + ((size_t)b * LL + qrow) * DD + 4 * g;
#pragma unroll
        for (int dt = 0; dt < 16; ++dt) {
            f32x4 vv = o[dt] * zinv;
            *(f32x4*)(orow + dt * 16) = vv;
        }
    }
}

extern "C" void kernel_launch(void* const* d_in, const int* in_sizes, int n_in,
                              void* d_out, int out_size, void* d_ws, size_t ws_size,
                              hipStream_t stream)
{
    const float* v1      = (const float*)d_in[0];
    const void*  v1_mask = d_in[1];
    const float* v2      = (const float*)d_in[2];
    const void*  v2_mask = d_in[3];
    float* out = (float*)d_out;

    const size_t ELEMS = (size_t)NB * LL * DD;  // 16,777,216
    u16* v1h = (u16*)d_ws;
    u16* v1l = v1h + ELEMS;
    u16* v2h = v1l + ELEMS;
    u16* v2l = v2h + ELEMS;
    u16* v1t = v2l + ELEMS;
    u16* v2t = v1t + ELEMS;
    int* qidx1 = (int*)(v2t + ELEMS);
    int* qcnt1 = qidx1 + NB * LL;
    int* qidx2 = qcnt1 + NB;
    int* qcnt2 = qidx2 + NB * LL;
    int* cm1   = qcnt2 + NB;          // canonical int32 masks
    int* cm2   = cm1 + NB * LL;
    int* mflag = cm2 + NB * LL;
    // ws requirement: 6*ELEMS*2 + ~1.3 MB of int scratch ~= 203 MB

    hipMemsetAsync(d_out, 0, (size_t)out_size * sizeof(float), stream);

    mask_detect<<<dim3(1), dim3(256), 0, stream>>>(
        (const unsigned*)v1_mask, (const unsigned*)v2_mask, mflag);
    mask_convert<<<dim3(NB * LL / 256), dim3(256), 0, stream>>>(v1_mask, mflag, cm1);
    mask_convert<<<dim3(NB * LL / 256), dim3(256), 0, stream>>>(v2_mask, mflag, cm2);

    prep_kernel<<<dim3(NB * 64), dim3(256), 0, stream>>>(v1, v1h, v1l, v1t);
    prep_kernel<<<dim3(NB * 64), dim3(256), 0, stream>>>(v2, v2h, v2l, v2t);
    build_qidx<<<dim3(NB), dim3(256), 0, stream>>>(cm1, qidx1, qcnt1);
    build_qidx<<<dim3(NB), dim3(256), 0, stream>>>(cm2, qidx2, qcnt2);

    // dir A: attended_v1 (Q=v1, K/V=v2, key mask = v2_mask, queries compacted by v1_mask)
    flash_kernel<<<dim3(NB * 16), dim3(256), 0, stream>>>(
        v1h, v1l, v2h, v2l, v2t, cm2, qidx1, qcnt1, out);
    // dir B: attended_v2 (Q=v2, K/V=v1)
    flash_kernel<<<dim3(NB * 16), dim3(256), 0, stream>>>(
        v2h, v2l, v1h, v1l, v1t, cm1, qidx2, qcnt2, out + ELEMS);
}